// Round 16
// baseline (475.751 us; speedup 1.0000x reference)
//
#include <hip/hip_runtime.h>

#define N_ 256
#define C_ 2048
#define HW_ 49
#define CPB 64
#define NCC 32          // 64-ch chunks (k_mul / fallback k_main)
#define NCHUNK 8        // 256-ch chunks (k_poolpp / k_poolc_fb)
#define PROWS 2054      // pool rows: 3 halo + 2048 + 3 halo

// ============================================================================
// MAIN PATH
// ============================================================================

// ---- kernel 1: channel-pool partials + W/H pool planes -> global ----
// r8 k_poolc (BW-floor, 15us) + per-pass register/LDS pool computation hidden
// under the BW; pools flushed coalesced. pools[n][f][PROWS][8], f = conv*2+i2.
__global__ __launch_bounds__(256) void k_poolpp(const float* __restrict__ x,
    float* __restrict__ psum, float* __restrict__ pmax,
    float* __restrict__ pools) {
  const int bc = blockIdx.x, n = blockIdx.y;
  const int t = threadIdx.x;
  __shared__ __align__(16) float sx[CPB * HW_];     // 12.5 KB
  __shared__ __align__(16) float ptile[4 * 64 * 8]; // 8 KB
  __shared__ float part_s[HW_][5];
  __shared__ float part_m[HW_][5];

  float sm = 0.f, mx = -3.4e38f;
  const int hw = t / 5, s = t % 5;
  const float4* xv = (const float4*)(x + ((size_t)n * C_ + (size_t)bc * 256) * HW_);
  float4* sv = (float4*)sx;
  const float4* ptv = (const float4*)ptile;

#define FLUSH(PASS) { \
    int c0p = bc * 256 + (PASS) * 64; \
    for (int i = t; i < 512; i += 256) { \
      int f_ = i >> 7, r_ = (i >> 1) & 63, h_ = i & 1; \
      float4* dst = (float4*)(pools + (((size_t)n * 4 + f_) * PROWS + 3 + c0p + r_) * 8); \
      dst[h_] = ptv[(f_ * 64 + r_) * 2 + h_]; \
    } }

  #pragma unroll
  for (int pass = 0; pass < 4; ++pass) {
    for (int v = t; v < 784; v += 256) sv[v] = xv[pass * 784 + v];
    if (pass > 0) FLUSH(pass - 1);
    __syncthreads();
    if (t < 245) {                        // channel-pool partials (g_hw input)
      #pragma unroll
      for (int j = 0; j < 13; ++j) {
        int c = s * 13 + j;
        if (c < CPB) { float a = sx[c * HW_ + hw]; sm += a; mx = fmaxf(mx, a); }
      }
    }
    for (int i = t; i < 448; i += 256) {  // W/H pools for the 64 staged channels
      int lc = i / 7, k = i % 7;
      int base = lc * HW_;
      float s1 = 0.f, m1 = -3.4e38f, s2 = 0.f, m2 = -3.4e38f;
      #pragma unroll
      for (int j = 0; j < 7; ++j) {
        float a = sx[base + k * 7 + j]; s1 += a; m1 = fmaxf(m1, a);  // h=k vary w
        float b = sx[base + j * 7 + k]; s2 += b; m2 = fmaxf(m2, b);  // w=k vary h
      }
      ptile[(0 * 64 + lc) * 8 + k] = s1 * (1.f / 7.f);  // f0: g_ch mean(W)
      ptile[(1 * 64 + lc) * 8 + k] = m1;                // f1: g_ch max(W)
      ptile[(2 * 64 + lc) * 8 + k] = s2 * (1.f / 7.f);  // f2: g_cw mean(H)
      ptile[(3 * 64 + lc) * 8 + k] = m2;                // f3: g_cw max(H)
    }
    __syncthreads();
  }
  FLUSH(3);
#undef FLUSH
  // zero halo rows (channels outside [0,C) have pool value 0)
  if (bc == 0 && t >= 64 && t < 88) {
    int tt = t - 64, f = tt / 6, i = tt % 6;     // 3 rows x 2 f4 per plane
    float4* dst = (float4*)(pools + (((size_t)n * 4 + f) * PROWS) * 8);
    dst[i] = make_float4(0.f, 0.f, 0.f, 0.f);
  }
  if (bc == NCHUNK - 1 && t >= 96 && t < 120) {
    int tt = t - 96, f = tt / 6, i = tt % 6;
    float4* dst = (float4*)(pools + (((size_t)n * 4 + f) * PROWS + 2051) * 8);
    dst[i] = make_float4(0.f, 0.f, 0.f, 0.f);
  }
  if (t < 245) { part_s[hw][s] = sm; part_m[hw][s] = mx; }
  __syncthreads();
  if (t < HW_) {
    float s2 = 0.f, m2 = -3.4e38f;
    #pragma unroll
    for (int k = 0; k < 5; ++k) { s2 += part_s[t][k]; m2 = fmaxf(m2, part_m[t][k]); }
    size_t o = ((size_t)n * NCHUNK + bc) * HW_ + t;
    psum[o] = s2; pmax[o] = m2;
  }
}

// ---- kernel 2: per-channel dual conv from pools -> gates. Zero LDS/barriers ----
__global__ __launch_bounds__(256, 4) void k_gaten(const float* __restrict__ pools,
    const float* __restrict__ cw, const float* __restrict__ cb,
    const float* __restrict__ bnw, const float* __restrict__ bnb,
    const float* __restrict__ bnrm, const float* __restrict__ bnrv,
    float* __restrict__ gch_g, float* __restrict__ gcw_g) {
  const int c = blockIdx.x * 256 + threadIdx.x;   // channel
  const int n = blockIdx.y;

  const float cb0 = cb[0];
  const float sc1 = bnw[1] * rsqrtf(bnrv[1] + 1e-5f), rm1 = bnrm[1], sh1 = bnb[1];
  const float sc2 = bnw[2] * rsqrtf(bnrv[2] + 1e-5f), rm2 = bnrm[2], sh2 = bnb[2];

  const float* pb = pools + (size_t)n * 4 * PROWS * 8;
  float acc0[7] = {0.f, 0.f, 0.f, 0.f, 0.f, 0.f, 0.f};   // g_ch pre-BN
  float acc1[7] = {0.f, 0.f, 0.f, 0.f, 0.f, 0.f, 0.f};   // g_cw pre-BN

  #pragma unroll
  for (int p = 0; p < 7; ++p) {
    // rows c..c+6 = channels c-3..c+3 (halo rows pre-zeroed). 32B-aligned.
    const float* rowA = pb + ((size_t)0 * PROWS + c + p) * 8;
    const float* rowB = pb + ((size_t)1 * PROWS + c + p) * 8;
    const float* rowC = pb + ((size_t)2 * PROWS + c + p) * 8;
    const float* rowD = pb + ((size_t)3 * PROWS + c + p) * 8;
    float4 a0 = *(const float4*)rowA, a1 = *(const float4*)(rowA + 4);
    float4 b0 = *(const float4*)rowB, b1 = *(const float4*)(rowB + 4);
    float4 c0 = *(const float4*)rowC, c1 = *(const float4*)(rowC + 4);
    float4 d0 = *(const float4*)rowD, d1 = *(const float4*)(rowD + 4);
    float rA[7] = {a0.x, a0.y, a0.z, a0.w, a1.x, a1.y, a1.z};
    float rB[7] = {b0.x, b0.y, b0.z, b0.w, b1.x, b1.y, b1.z};
    float rC[7] = {c0.x, c0.y, c0.z, c0.w, c1.x, c1.y, c1.z};
    float rD[7] = {d0.x, d0.y, d0.z, d0.w, d1.x, d1.y, d1.z};
    #pragma unroll
    for (int q = 0; q < 7; ++q) {
      float w0 = cw[p * 7 + q];        // uniform -> scalar load
      float w1 = cw[49 + p * 7 + q];
      #pragma unroll
      for (int k = 0; k < 7; ++k) {
        int cc = k + q - 3;            // compile-time after unroll
        if (cc >= 0 && cc < 7) {
          acc0[k] += rA[cc] * w0 + rB[cc] * w1;
          acc1[k] += rC[cc] * w0 + rD[cc] * w1;
        }
      }
    }
  }
  float* g1 = gch_g + ((size_t)n * C_ + c) * 7;
  float* g2 = gcw_g + ((size_t)n * C_ + c) * 7;
  #pragma unroll
  for (int k = 0; k < 7; ++k) {
    float y0 = (acc0[k] + cb0 - rm1) * sc1 + sh1;
    y0 = fmaxf(y0, 0.f);
    g1[k] = 1.f / (1.f + __expf(-y0));
    float y1 = (acc1[k] + cb0 - rm2) * sc2 + sh2;
    y1 = fmaxf(y1, 0.f);
    g2[k] = 1.f / (1.f + __expf(-y1));
  }
}

// ---- kernel 3: reduce partials, g_hw gate per n ----
__global__ __launch_bounds__(64) void k_ghw(const float* __restrict__ psum,
                                            const float* __restrict__ pmax,
                                            const float* __restrict__ cw,
                                            const float* __restrict__ cb,
                                            const float* __restrict__ bnw,
                                            const float* __restrict__ bnb,
                                            const float* __restrict__ bnrm,
                                            const float* __restrict__ bnrv,
                                            float* __restrict__ ghw) {
  const int n = blockIdx.x;
  const int t = threadIdx.x;
  __shared__ float p2c[2][13][13];
  __shared__ float s_cw[98];

  for (int i = t; i < 2 * 13 * 13; i += 64) ((float*)p2c)[i] = 0.f;
  for (int i = t; i < 98; i += 64) s_cw[i] = cw[i];
  __syncthreads();

  if (t < HW_) {
    float sm = 0.f, mx = -3.4e38f;
    const float* ps = psum + (size_t)n * NCHUNK * HW_ + t;
    const float* pm = pmax + (size_t)n * NCHUNK * HW_ + t;
    #pragma unroll
    for (int cc = 0; cc < NCHUNK; ++cc) {
      sm += ps[cc * HW_];
      mx = fmaxf(mx, pm[cc * HW_]);
    }
    p2c[0][t / 7 + 3][t % 7 + 3] = sm * (1.f / C_);
    p2c[1][t / 7 + 3][t % 7 + 3] = mx;
  }
  __syncthreads();

  if (t < HW_) {
    int a = t / 7, b = t % 7;
    float y = cb[0];
    #pragma unroll
    for (int i2 = 0; i2 < 2; ++i2)
      #pragma unroll
      for (int p = 0; p < 7; ++p)
        #pragma unroll
        for (int q = 0; q < 7; ++q)
          y += p2c[i2][a + p][b + q] * s_cw[i2 * 49 + p * 7 + q];
    float sc = bnw[0] * rsqrtf(bnrv[0] + 1e-5f);
    y = (y - bnrm[0]) * sc + bnb[0];
    y = fmaxf(y, 0.f);
    ghw[n * HW_ + t] = 1.f / (1.f + __expf(-y));
  }
}

// ---- kernel 4: pure streaming fused multiply (r9-proven, ~14us) ----
__global__ __launch_bounds__(256) void k_mul(const float* __restrict__ x,
    const float* __restrict__ ghw, const float* __restrict__ gch_g,
    const float* __restrict__ gcw_g, float* __restrict__ out) {
  const int cc = blockIdx.x;
  const int n  = (N_ - 1) - blockIdx.y;   // reverse n: read freshest L3 lines
  const int c0 = cc * CPB;
  const int t  = threadIdx.x;

  __shared__ float sg[960];  // [0,448) gch, [448,896) gcw, [896,945) ghw

  {
    const float* g1 = gch_g + ((size_t)n * C_ + c0) * 7;
    const float* g2 = gcw_g + ((size_t)n * C_ + c0) * 7;
    for (int i = t; i < 945; i += 256) {
      float v;
      if (i < 448)      v = g1[i];
      else if (i < 896) v = g2[i - 448];
      else              v = ghw[n * HW_ + (i - 896)];
      sg[i] = v;
    }
  }
  __syncthreads();
  const float* gch = sg;
  const float* gcw = sg + 448;
  const float* s_ghw = sg + 896;

  const float4* xv = (const float4*)(x + ((size_t)n * C_ + c0) * HW_);
  float4* outv = (float4*)(out + ((size_t)n * C_ + c0) * HW_);
  for (int v = t; v < 784; v += 256) {
    float4 q = xv[v];
    int e0 = v * 4;
    int cj = e0 / 49;
    int hw0 = e0 - cj * 49;
    float r[4] = {q.x, q.y, q.z, q.w};
    #pragma unroll
    for (int j = 0; j < 4; ++j) {
      int hw = hw0 + j;
      int cjj = cj + (hw >= 49);
      hw -= (hw >= 49) ? 49 : 0;
      int h = (hw * 37) >> 8, w2 = hw - h * 7;
      r[j] *= (s_ghw[hw] + gch[cjj * 7 + h] + gcw[cjj * 7 + w2]) * (1.f / 3.f);
    }
    outv[v] = make_float4(r[0], r[1], r[2], r[3]);
  }
}

// ============================================================================
// FALLBACK PATH (r13, 79us proven) — if ws too small for pools+gates
// ============================================================================
#define CHB(lc) ((lc) * HW_ + ((lc) >= 3 ? 1 : 0))

__global__ __launch_bounds__(256) void k_poolc_fb(const float* __restrict__ x,
                                                  float* __restrict__ psum,
                                                  float* __restrict__ pmax) {
  const int bc = blockIdx.x, n = blockIdx.y;
  const int t = threadIdx.x;
  __shared__ __align__(16) float sx[CPB * HW_];
  __shared__ float part_s[HW_][5];
  __shared__ float part_m[HW_][5];

  float sm = 0.f, mx = -3.4e38f;
  const int hw = t / 5, s = t % 5;

  const float4* xv = (const float4*)(x + ((size_t)n * C_ + (size_t)bc * 256) * HW_);
  #pragma unroll
  for (int pass = 0; pass < 4; ++pass) {
    float4* sv = (float4*)sx;
    for (int v = t; v < 784; v += 256) sv[v] = xv[pass * 784 + v];
    __syncthreads();
    if (t < 245) {
      #pragma unroll
      for (int j = 0; j < 13; ++j) {
        int c = s * 13 + j;
        if (c < CPB) { float a = sx[c * HW_ + hw]; sm += a; mx = fmaxf(mx, a); }
      }
    }
    __syncthreads();
  }
  if (t < 245) { part_s[hw][s] = sm; part_m[hw][s] = mx; }
  __syncthreads();
  if (t < HW_) {
    float s2 = 0.f, m2 = -3.4e38f;
    #pragma unroll
    for (int k = 0; k < 5; ++k) { s2 += part_s[t][k]; m2 = fmaxf(m2, part_m[t][k]); }
    size_t o = ((size_t)n * NCHUNK + bc) * HW_ + t;
    psum[o] = s2; pmax[o] = m2;
  }
}

__global__ __launch_bounds__(256, 6) void k_main_fb(const float* __restrict__ x,
    const float* __restrict__ ghw,
    const float* __restrict__ cw, const float* __restrict__ cb,
    const float* __restrict__ bnw, const float* __restrict__ bnb,
    const float* __restrict__ bnrm, const float* __restrict__ bnrv,
    float* __restrict__ out) {
  const int cc = blockIdx.x;
  const int n  = (N_ - 1) - blockIdx.y;
  const int c0 = cc * CPB;
  const int t  = threadIdx.x;

  __shared__ __align__(16) float sx[3432];
  __shared__ __align__(16) float pool_lo[1120];
  __shared__ __align__(16) float pool_hi[1120];
  __shared__ float gch[448];
  __shared__ float gcw[448];
  __shared__ __align__(16) float s_w[112];
  __shared__ float s_ghw[49];

  const int conv = t & 1, i2 = (t >> 1) & 1, cl = t >> 2;
  const int bi = 1 + conv;
  const float cb0 = cb[0];
  const float sc_bn = bnw[bi] * rsqrtf(bnrv[bi] + 1e-5f);
  const float rm_bn = bnrm[bi];
  const float sh_bn = bnb[bi];

  if (t < 112) {
    int i2w = t / 56, rem = t % 56, p = rem / 8, q = rem % 8;
    s_w[t] = (q < 7) ? cw[i2w * 49 + p * 7 + q] : 0.f;
  }
  if (t < HW_) s_ghw[t] = ghw[n * HW_ + t];
  for (int i = t; i < 2 * 3 * HW_; i += 256) {
    int side = i / 147, off = i % 147;
    int lc = side ? (67 + off / HW_) : (off / HW_);
    int c = c0 - 3 + lc;
    float vv = 0.f;
    if (c >= 0 && c < C_) vv = x[((size_t)n * C_ + c) * HW_ + off % HW_];
    sx[CHB(lc) + off % HW_] = vv;
  }
  const float4* xv = (const float4*)(x + ((size_t)n * C_ + c0) * HW_);
  float4* sxv = (float4*)(sx + 148);
  for (int v = t; v < 784; v += 256) sxv[v] = xv[v];
  __syncthreads();

  for (int i = t; i < 70 * 7; i += 256) {
    int lc = i / 7, k = i % 7;
    int base = CHB(lc);
    float s1 = 0.f, m1 = -3.4e38f, s2 = 0.f, m2 = -3.4e38f;
    #pragma unroll
    for (int j = 0; j < 7; ++j) {
      float a = sx[base + k * 7 + j]; s1 += a; m1 = fmaxf(m1, a);
      float b = sx[base + j * 7 + k]; s2 += b; m2 = fmaxf(m2, b);
    }
    float* pb = (k < 4) ? pool_lo : pool_hi;
    int kk = k & 3;
    pb[(0 * 70 + lc) * 4 + kk] = s1 * (1.f / 7.f);
    pb[(1 * 70 + lc) * 4 + kk] = m1;
    pb[(2 * 70 + lc) * 4 + kk] = s2 * (1.f / 7.f);
    pb[(3 * 70 + lc) * 4 + kk] = m2;
  }
  __syncthreads();

  {
    const int f = conv * 2 + i2;
    const float* Wb = s_w + i2 * 56;
    float acc[7] = {0.f, 0.f, 0.f, 0.f, 0.f, 0.f, 0.f};
    #pragma unroll
    for (int p = 0; p < 7; ++p) {
      int ri = (f * 70 + cl + p) * 4;
      float4 r0 = *(const float4*)(pool_lo + ri);
      float4 r1 = *(const float4*)(pool_hi + ri);
      float row[7] = {r0.x, r0.y, r0.z, r0.w, r1.x, r1.y, r1.z};
      float4 w0 = *(const float4*)(Wb + p * 8);
      float4 w1 = *(const float4*)(Wb + p * 8 + 4);
      float wr[7] = {w0.x, w0.y, w0.z, w0.w, w1.x, w1.y, w1.z};
      #pragma unroll
      for (int q = 0; q < 7; ++q)
        #pragma unroll
        for (int k = 0; k < 7; ++k) {
          int c = k + q - 3;
          if (c >= 0 && c < 7) acc[k] += row[c] * wr[q];
        }
    }
    float fsum[7];
    #pragma unroll
    for (int k = 0; k < 7; ++k) fsum[k] = acc[k] + __shfl_xor(acc[k], 2, 64);
    if (i2 == 0) {
      float* gp = (conv ? gcw : gch) + cl * 7;
      #pragma unroll
      for (int k = 0; k < 7; ++k) {
        float y = (fsum[k] + cb0 - rm_bn) * sc_bn + sh_bn;
        y = fmaxf(y, 0.f);
        gp[k] = 1.f / (1.f + __expf(-y));
      }
    }
  }
  __syncthreads();

  float4* outv = (float4*)(out + ((size_t)n * C_ + c0) * HW_);
  for (int v = t; v < 784; v += 256) {
    float4 q = sxv[v];
    int e0 = v * 4;
    int cj = e0 / 49;
    int hw0 = e0 - cj * 49;
    float r[4] = {q.x, q.y, q.z, q.w};
    #pragma unroll
    for (int j = 0; j < 4; ++j) {
      int hw = hw0 + j;
      int cjj = cj + (hw >= 49);
      hw -= (hw >= 49) ? 49 : 0;
      int h = (hw * 37) >> 8, w2 = hw - h * 7;
      r[j] *= (s_ghw[hw] + gch[cjj * 7 + h] + gcw[cjj * 7 + w2]) * (1.f / 3.f);
    }
    outv[v] = make_float4(r[0], r[1], r[2], r[3]);
  }
}

extern "C" void kernel_launch(void* const* d_in, const int* in_sizes, int n_in,
                              void* d_out, int out_size, void* d_ws, size_t ws_size,
                              hipStream_t stream) {
  const float* x    = (const float*)d_in[0];
  const float* cw   = (const float*)d_in[1];
  const float* cb   = (const float*)d_in[2];
  const float* bnw  = (const float*)d_in[3];
  const float* bnb  = (const float*)d_in[4];
  const float* bnrm = (const float*)d_in[5];
  const float* bnrv = (const float*)d_in[6];
  float* out = (float*)d_out;

  float* psum  = (float*)d_ws;                          // N*8*49
  float* pmax  = psum + (size_t)N_ * NCHUNK * HW_;      // N*8*49
  float* ghw   = pmax + (size_t)N_ * NCHUNK * HW_;      // N*49
  float* gch_g = ghw + (size_t)N_ * HW_;                // N*C*7
  float* gcw_g = gch_g + (size_t)N_ * C_ * 7;           // N*C*7
  float* pools = gcw_g + (size_t)N_ * C_ * 7;           // N*4*PROWS*8
  size_t need_floats = (size_t)N_ * NCHUNK * HW_ * 2 + (size_t)N_ * HW_
                     + (size_t)N_ * C_ * 7 * 2
                     + (size_t)N_ * 4 * PROWS * 8;

  if (ws_size >= need_floats * sizeof(float)) {
    k_poolpp<<<dim3(NCHUNK, N_), 256, 0, stream>>>(x, psum, pmax, pools);
    k_gaten<<<dim3(C_ / 256, N_), 256, 0, stream>>>(pools, cw, cb, bnw, bnb,
                                                    bnrm, bnrv, gch_g, gcw_g);
    k_ghw<<<dim3(N_), 64, 0, stream>>>(psum, pmax, cw, cb, bnw, bnb, bnrm, bnrv, ghw);
    k_mul<<<dim3(NCC, N_), 256, 0, stream>>>(x, ghw, gch_g, gcw_g, out);
  } else {
    k_poolc_fb<<<dim3(NCHUNK, N_), 256, 0, stream>>>(x, psum, pmax);
    k_ghw<<<dim3(N_), 64, 0, stream>>>(psum, pmax, cw, cb, bnw, bnb, bnrm, bnrv, ghw);
    k_main_fb<<<dim3(NCC, N_), 256, 0, stream>>>(x, ghw, cw, cb, bnw, bnb, bnrm,
                                                 bnrv, out);
  }
}

// Round 17
// 86.765 us; speedup vs baseline: 5.4832x; 5.4832x over previous
//
#include <hip/hip_runtime.h>

#define N_ 256
#define C_ 2048
#define HW_ 49
#define NCHUNK 8        // 256-ch chunks in k_poolc
#define CPT 16          // channels per wave-tile
#define NCT (C_/CPT)    // 128 tiles per n
#define PSTRIDE 184     // pool plane stride (23 rows x 8; 184%32=24 -> even banks)

// ---------------- kernel 1: channel-pool partials, 256 ch per block (r8) ----------------
__global__ __launch_bounds__(256) void k_poolc(const float* __restrict__ x,
                                               float* __restrict__ psum,
                                               float* __restrict__ pmax) {
  const int bc = blockIdx.x, n = blockIdx.y;
  const int t = threadIdx.x;
  __shared__ __align__(16) float sx[64 * HW_];
  __shared__ float part_s[HW_][5];
  __shared__ float part_m[HW_][5];

  float sm = 0.f, mx = -3.4e38f;
  const int hw = t / 5, s = t % 5;

  const float4* xv = (const float4*)(x + ((size_t)n * C_ + (size_t)bc * 256) * HW_);
  #pragma unroll
  for (int pass = 0; pass < 4; ++pass) {
    float4* sv = (float4*)sx;
    for (int v = t; v < 784; v += 256) sv[v] = xv[pass * 784 + v];
    __syncthreads();
    if (t < 245) {
      #pragma unroll
      for (int j = 0; j < 13; ++j) {
        int c = s * 13 + j;
        if (c < 64) { float a = sx[c * HW_ + hw]; sm += a; mx = fmaxf(mx, a); }
      }
    }
    __syncthreads();
  }
  if (t < 245) { part_s[hw][s] = sm; part_m[hw][s] = mx; }
  __syncthreads();
  if (t < HW_) {
    float s2 = 0.f, m2 = -3.4e38f;
    #pragma unroll
    for (int k = 0; k < 5; ++k) { s2 += part_s[t][k]; m2 = fmaxf(m2, part_m[t][k]); }
    size_t o = ((size_t)n * NCHUNK + bc) * HW_ + t;
    psum[o] = s2; pmax[o] = m2;
  }
}

// ---------------- kernel 2: reduce chunks, compute g_hw gate per n ----------------
__global__ __launch_bounds__(64) void k_ghw(const float* __restrict__ psum,
                                            const float* __restrict__ pmax,
                                            const float* __restrict__ cw,
                                            const float* __restrict__ cb,
                                            const float* __restrict__ bnw,
                                            const float* __restrict__ bnb,
                                            const float* __restrict__ bnrm,
                                            const float* __restrict__ bnrv,
                                            float* __restrict__ ghw) {
  const int n = blockIdx.x;
  const int t = threadIdx.x;
  __shared__ float p2c[2][13][13];
  __shared__ float s_cw[98];

  for (int i = t; i < 2 * 13 * 13; i += 64) ((float*)p2c)[i] = 0.f;
  for (int i = t; i < 98; i += 64) s_cw[i] = cw[i];
  __syncthreads();

  if (t < HW_) {
    float sm = 0.f, mx = -3.4e38f;
    const float* ps = psum + (size_t)n * NCHUNK * HW_ + t;
    const float* pm = pmax + (size_t)n * NCHUNK * HW_ + t;
    #pragma unroll
    for (int cc = 0; cc < NCHUNK; ++cc) {
      sm += ps[cc * HW_];
      mx = fmaxf(mx, pm[cc * HW_]);
    }
    p2c[0][t / 7 + 3][t % 7 + 3] = sm * (1.f / C_);
    p2c[1][t / 7 + 3][t % 7 + 3] = mx;
  }
  __syncthreads();

  if (t < HW_) {
    int a = t / 7, b = t % 7;
    float y = cb[0];
    #pragma unroll
    for (int i2 = 0; i2 < 2; ++i2)
      #pragma unroll
      for (int p = 0; p < 7; ++p)
        #pragma unroll
        for (int q = 0; q < 7; ++q)
          y += p2c[i2][a + p][b + q] * s_cw[i2 * 49 + p * 7 + q];
    float sc = bnw[0] * rsqrtf(bnrv[0] + 1e-5f);
    y = (y - bnrm[0]) * sc + bnb[0];
    y = fmaxf(y, 0.f);
    ghw[n * HW_ + t] = 1.f / (1.f + __expf(-y));
  }
}

// ---------------- kernel 3: single-wave tiles — pools, conv, multiply ----------------
// One 64-lane wave owns 16 channels. No inter-wave sync (1 wave/block).
// LDS 7.8 KB -> ~20 blocks/CU, all independent. Conv: one (cl,conv,i2) per lane.
__global__ __launch_bounds__(64) void k_w64(const float* __restrict__ x,
    const float* __restrict__ ghw,
    const float* __restrict__ cw, const float* __restrict__ cb,
    const float* __restrict__ bnw, const float* __restrict__ bnb,
    const float* __restrict__ bnrm, const float* __restrict__ bnrv,
    float* __restrict__ out) {
  const int bc = blockIdx.x;                 // tile: channels bc*16 .. +15
  const int n  = (N_ - 1) - blockIdx.y;      // reverse n: L3-freshest first
  const int c0 = bc * CPT;
  const int lane = threadIdx.x;

  __shared__ __align__(16) float sx[CPT * 52];     // 832: main ch, stride 52
  __shared__ __align__(16) float pools[4 * PSTRIDE];  // 736: [f][23 rows][8]
  __shared__ __align__(16) float s_w[112];         // [2][7][8] q-padded
  __shared__ float gch[112];                       // [16][7]
  __shared__ float gcw[112];
  __shared__ float s_ghw[49];

  // ---- stage: weights, ghw slice, 16 main channels (coalesced float4) ----
  for (int i = lane; i < 112; i += 64) {
    int i2w = i / 56, rem = i % 56, p = rem / 8, q = rem % 8;
    s_w[i] = (q < 7) ? cw[i2w * 49 + p * 7 + q] : 0.f;
  }
  if (lane < HW_) s_ghw[lane] = ghw[n * HW_ + lane];
  const float4* xv = (const float4*)(x + ((size_t)n * C_ + c0) * HW_);
  #pragma unroll
  for (int m = 0; m < 4; ++m) {
    int v = lane + m * 64;
    if (v < 196) {
      float4 q = xv[v];
      int e = v * 4, ch = e / 49, pos = e - ch * 49;
      int base = ch * 52 + pos;
      sx[base] = q.x;
      sx[base + 1 + ((pos >= 48) ? 3 : 0)] = q.y;
      sx[base + 2 + ((pos >= 47) ? 3 : 0)] = q.z;
      sx[base + 3 + ((pos >= 46) ? 3 : 0)] = q.w;
    }
  }
  __syncthreads();   // single wave: s_waitcnt + immediate barrier

  // ---- pools: 22 rows x 7 k = 154 items; row r <-> channel c0-3+r ----
  #pragma unroll
  for (int it = 0; it < 3; ++it) {
    int i = lane + it * 64;
    if (i < 154) {
      int ch = i / 7, k = i % 7;               // ch = pool row 0..21
      float s1 = 0.f, m1, s2 = 0.f, m2;
      if (ch >= 3 && ch < 19) {                // main channel: from LDS
        int base = (ch - 3) * 52;
        m1 = -3.4e38f; m2 = -3.4e38f;
        #pragma unroll
        for (int j = 0; j < 7; ++j) {
          float a = sx[base + k * 7 + j]; s1 += a; m1 = fmaxf(m1, a);  // h=k vary w
          float b = sx[base + j * 7 + k]; s2 += b; m2 = fmaxf(m2, b);  // w=k vary h
        }
        s1 *= (1.f / 7.f); s2 *= (1.f / 7.f);
      } else {                                 // halo channel: global (L2-hot)
        int c = c0 - 3 + ch;
        bool ok = (c >= 0 && c < C_);
        m1 = ok ? -3.4e38f : 0.f; m2 = m1;
        if (ok) {
          const float* xp = x + ((size_t)n * C_ + c) * HW_;
          #pragma unroll
          for (int j = 0; j < 7; ++j) {
            float a = xp[k * 7 + j]; s1 += a; m1 = fmaxf(m1, a);
            float b = xp[j * 7 + k]; s2 += b; m2 = fmaxf(m2, b);
          }
          s1 *= (1.f / 7.f); s2 *= (1.f / 7.f);
        }
      }
      pools[0 * PSTRIDE + ch * 8 + k] = s1;    // f0: g_ch mean(W)
      pools[1 * PSTRIDE + ch * 8 + k] = m1;    // f1: g_ch max(W)
      pools[2 * PSTRIDE + ch * 8 + k] = s2;    // f2: g_cw mean(H)
      pools[3 * PSTRIDE + ch * 8 + k] = m2;    // f3: g_cw max(H)
    }
  }
  __syncthreads();

  // ---- conv: lane = cl*4 + conv*2 + i2 (one unit per lane) ----
  {
    const int cl = lane >> 2, conv = (lane >> 1) & 1, i2 = lane & 1;
    const int f = conv * 2 + i2;
    const float* Wb = s_w + i2 * 56;           // 2 distinct addrs/wave: 2-way, free
    float acc[7] = {0.f, 0.f, 0.f, 0.f, 0.f, 0.f, 0.f};
    #pragma unroll
    for (int p = 0; p < 7; ++p) {
      int ri = f * PSTRIDE + (cl + p) * 8;     // rows cl..cl+6 = channels c-3..c+3
      float4 r0 = *(const float4*)(pools + ri);
      float4 r1 = *(const float4*)(pools + ri + 4);
      float row[7] = {r0.x, r0.y, r0.z, r0.w, r1.x, r1.y, r1.z};
      float4 w0 = *(const float4*)(Wb + p * 8);
      float4 w1 = *(const float4*)(Wb + p * 8 + 4);
      float wr[7] = {w0.x, w0.y, w0.z, w0.w, w1.x, w1.y, w1.z};
      #pragma unroll
      for (int q = 0; q < 7; ++q)
        #pragma unroll
        for (int k = 0; k < 7; ++k) {
          int c = k + q - 3;                   // compile-time after unroll
          if (c >= 0 && c < 7) acc[k] += row[c] * wr[q];
        }
    }
    float fsum[7];
    #pragma unroll
    for (int k = 0; k < 7; ++k) fsum[k] = acc[k] + __shfl_xor(acc[k], 1, 64);
    const int bi = 1 + conv;
    const float cb0 = cb[0];
    const float sc_bn = bnw[bi] * rsqrtf(bnrv[bi] + 1e-5f);
    const float rm_bn = bnrm[bi];
    const float sh_bn = bnb[bi];
    if (i2 == 0) {
      float* gp = (conv ? gcw : gch) + cl * 7;
      #pragma unroll
      for (int k = 0; k < 7; ++k) {
        float y = (fsum[k] + cb0 - rm_bn) * sc_bn + sh_bn;
        y = fmaxf(y, 0.f);
        gp[k] = 1.f / (1.f + __expf(-y));
      }
    }
  }
  __syncthreads();

  // ---- multiply: re-read x from global (L1/L2-hot, coalesced), store out ----
  float4* outv = (float4*)(out + ((size_t)n * C_ + c0) * HW_);
  #pragma unroll
  for (int m = 0; m < 4; ++m) {
    int v = lane + m * 64;
    if (v < 196) {
      float4 q = xv[v];
      int e0 = v * 4;
      int cj = e0 / 49;
      int hw0 = e0 - cj * 49;
      float r[4] = {q.x, q.y, q.z, q.w};
      #pragma unroll
      for (int j = 0; j < 4; ++j) {
        int hw = hw0 + j;
        int cjj = cj + (hw >= 49);
        hw -= (hw >= 49) ? 49 : 0;
        int h = (hw * 37) >> 8, w2 = hw - h * 7;
        r[j] *= (s_ghw[hw] + gch[cjj * 7 + h] + gcw[cjj * 7 + w2]) * (1.f / 3.f);
      }
      outv[v] = make_float4(r[0], r[1], r[2], r[3]);
    }
  }
}

extern "C" void kernel_launch(void* const* d_in, const int* in_sizes, int n_in,
                              void* d_out, int out_size, void* d_ws, size_t ws_size,
                              hipStream_t stream) {
  const float* x    = (const float*)d_in[0];
  const float* cw   = (const float*)d_in[1];
  const float* cb   = (const float*)d_in[2];
  const float* bnw  = (const float*)d_in[3];
  const float* bnb  = (const float*)d_in[4];
  const float* bnrm = (const float*)d_in[5];
  const float* bnrv = (const float*)d_in[6];
  float* out = (float*)d_out;

  float* psum = (float*)d_ws;                         // N*8*49
  float* pmax = psum + (size_t)N_ * NCHUNK * HW_;     // N*8*49
  float* ghw  = pmax + (size_t)N_ * NCHUNK * HW_;     // N*49

  k_poolc<<<dim3(NCHUNK, N_), 256, 0, stream>>>(x, psum, pmax);
  k_ghw<<<dim3(N_), 64, 0, stream>>>(psum, pmax, cw, cb, bnw, bnb, bnrm, bnrv, ghw);
  k_w64<<<dim3(NCT, N_), 64, 0, stream>>>(x, ghw, cw, cb, bnw, bnb, bnrm, bnrv, out);
}

// Round 18
// 78.482 us; speedup vs baseline: 6.0619x; 1.1055x over previous
//
#include <hip/hip_runtime.h>

#define N_ 256
#define C_ 2048
#define HW_ 49
#define CPB 64
#define NCHUNK 8        // 256-ch chunks in k_poolc
#define TPB 8           // tiles per block in k_main_p
#define NBX (C_/(CPB*TPB))   // 4 block-columns

// local-channel base in sx: 70 channels (3 halo low, 64 main, 3 halo high).
// Main chunk starts at 148 (16B-aligned for float4); halo-low at 0, gap at 147.
#define CHB(lc) ((lc) * HW_ + ((lc) >= 3 ? 1 : 0))

// ---------------- kernel 1: channel-pool partials, 256 ch per block (r8) ----------------
__global__ __launch_bounds__(256) void k_poolc(const float* __restrict__ x,
                                               float* __restrict__ psum,
                                               float* __restrict__ pmax) {
  const int bc = blockIdx.x, n = blockIdx.y;
  const int t = threadIdx.x;
  __shared__ __align__(16) float sx[CPB * HW_];
  __shared__ float part_s[HW_][5];
  __shared__ float part_m[HW_][5];

  float sm = 0.f, mx = -3.4e38f;
  const int hw = t / 5, s = t % 5;

  const float4* xv = (const float4*)(x + ((size_t)n * C_ + (size_t)bc * 256) * HW_);
  #pragma unroll
  for (int pass = 0; pass < 4; ++pass) {
    float4* sv = (float4*)sx;
    for (int v = t; v < 784; v += 256) sv[v] = xv[pass * 784 + v];
    __syncthreads();
    if (t < 245) {
      #pragma unroll
      for (int j = 0; j < 13; ++j) {
        int c = s * 13 + j;
        if (c < CPB) { float a = sx[c * HW_ + hw]; sm += a; mx = fmaxf(mx, a); }
      }
    }
    __syncthreads();
  }
  if (t < 245) { part_s[hw][s] = sm; part_m[hw][s] = mx; }
  __syncthreads();
  if (t < HW_) {
    float s2 = 0.f, m2 = -3.4e38f;
    #pragma unroll
    for (int k = 0; k < 5; ++k) { s2 += part_s[t][k]; m2 = fmaxf(m2, part_m[t][k]); }
    size_t o = ((size_t)n * NCHUNK + bc) * HW_ + t;
    psum[o] = s2; pmax[o] = m2;
  }
}

// ---------------- kernel 2: reduce chunks, compute g_hw gate per n ----------------
__global__ __launch_bounds__(64) void k_ghw(const float* __restrict__ psum,
                                            const float* __restrict__ pmax,
                                            const float* __restrict__ cw,
                                            const float* __restrict__ cb,
                                            const float* __restrict__ bnw,
                                            const float* __restrict__ bnb,
                                            const float* __restrict__ bnrm,
                                            const float* __restrict__ bnrv,
                                            float* __restrict__ ghw) {
  const int n = blockIdx.x;
  const int t = threadIdx.x;
  __shared__ float p2c[2][13][13];
  __shared__ float s_cw[98];

  for (int i = t; i < 2 * 13 * 13; i += 64) ((float*)p2c)[i] = 0.f;
  for (int i = t; i < 98; i += 64) s_cw[i] = cw[i];
  __syncthreads();

  if (t < HW_) {
    float sm = 0.f, mx = -3.4e38f;
    const float* ps = psum + (size_t)n * NCHUNK * HW_ + t;
    const float* pm = pmax + (size_t)n * NCHUNK * HW_ + t;
    #pragma unroll
    for (int cc = 0; cc < NCHUNK; ++cc) {
      sm += ps[cc * HW_];
      mx = fmaxf(mx, pm[cc * HW_]);
    }
    p2c[0][t / 7 + 3][t % 7 + 3] = sm * (1.f / C_);
    p2c[1][t / 7 + 3][t % 7 + 3] = mx;
  }
  __syncthreads();

  if (t < HW_) {
    int a = t / 7, b = t % 7;
    float y = cb[0];
    #pragma unroll
    for (int i2 = 0; i2 < 2; ++i2)
      #pragma unroll
      for (int p = 0; p < 7; ++p)
        #pragma unroll
        for (int q = 0; q < 7; ++q)
          y += p2c[i2][a + p][b + q] * s_cw[i2 * 49 + p * 7 + q];
    float sc = bnw[0] * rsqrtf(bnrv[0] + 1e-5f);
    y = (y - bnrm[0]) * sc + bnb[0];
    y = fmaxf(y, 0.f);
    ghw[n * HW_ + t] = 1.f / (1.f + __expf(-y));
  }
}

// ---------------- kernel 3: 8-tile pipelined gates + multiply (r15 structure) ----------------
// grid (4, N): block owns n and tiles cc = bx*8 .. bx*8+7. 1024 blocks = 4/CU.
// Per tile: issue next-tile loads -> P1 pools -> bar -> conv (load shadow)
//   -> regs->sx[next] -> bar -> multiply. LDS 40.6 KB -> 4 blk/CU.
__global__ __launch_bounds__(256, 4) void k_main_p(const float* __restrict__ x,
    const float* __restrict__ ghw,
    const float* __restrict__ cw, const float* __restrict__ cb,
    const float* __restrict__ bnw, const float* __restrict__ bnb,
    const float* __restrict__ bnrm, const float* __restrict__ bnrv,
    float* __restrict__ out) {
  const int bx = blockIdx.x;                  // 0..3
  const int n  = (N_ - 1) - blockIdx.y;       // reverse n: L3-freshest first
  const int t  = threadIdx.x;

  __shared__ __align__(16) float sx[2][3432];
  __shared__ __align__(16) float pool_lo[1120];  // [4][70][4] k=0..3
  __shared__ __align__(16) float pool_hi[1120];  // [4][70][4] k=4..6 (+pad)
  __shared__ float gch[448];
  __shared__ float gcw[448];
  __shared__ __align__(16) float s_w[112];       // [2][7][8] q-padded
  __shared__ float s_ghw[49];

  const int conv = t & 1, i2 = (t >> 1) & 1, cl = t >> 2;
  const int bi = 1 + conv;
  const float cb0 = cb[0];
  const float sc_bn = bnw[bi] * rsqrtf(bnrv[bi] + 1e-5f);
  const float rm_bn = bnrm[bi];
  const float sh_bn = bnb[bi];

  // ---- prologue: params + stage tile 0 into sx[0] ----
  if (t < 112) {
    int i2w = t / 56, rem = t % 56, p = rem / 8, q = rem % 8;
    s_w[t] = (q < 7) ? cw[i2w * 49 + p * 7 + q] : 0.f;
  }
  if (t < HW_) s_ghw[t] = ghw[n * HW_ + t];
  {
    const int c0 = (bx * TPB) * CPB;
    for (int i = t; i < 294; i += 256) {        // halo
      int side = i / 147, off = i % 147;
      int lc = side ? (67 + off / HW_) : (off / HW_);
      int c = c0 - 3 + lc;
      float vv = 0.f;
      if (c >= 0 && c < C_) vv = x[((size_t)n * C_ + c) * HW_ + off % HW_];
      sx[0][CHB(lc) + off % HW_] = vv;
    }
    const float4* xv = (const float4*)(x + ((size_t)n * C_ + c0) * HW_);
    float4* sxv = (float4*)(&sx[0][148]);
    for (int v = t; v < 784; v += 256) sxv[v] = xv[v];
  }
  __syncthreads();

  #pragma unroll 2
  for (int j = 0; j < TPB; ++j) {
    const int cur = j & 1, nxt = cur ^ 1;
    const int cc = bx * TPB + j;
    const int c0 = cc * CPB;
    float* sxc = sx[cur];

    // ---- issue next-tile loads (regs live until write below) ----
    float4 q0, q1, q2, q3;
    float h0, h1;
    if (j < TPB - 1) {
      const int c0n = (cc + 1) * CPB;
      const float4* xvn = (const float4*)(x + ((size_t)n * C_ + c0n) * HW_);
      if (t < 196) { q0 = xvn[t]; q1 = xvn[t + 196]; q2 = xvn[t + 392]; q3 = xvn[t + 588]; }
      if (t < 147) {
        int lcl = t / 49, off = t % 49;
        int cl_ = c0n - 3 + lcl;
        int ch_ = c0n + CPB + lcl;
        h0 = (cl_ >= 0 && cl_ < C_) ? x[((size_t)n * C_ + cl_) * HW_ + off] : 0.f;
        h1 = (ch_ < C_) ? x[((size_t)n * C_ + ch_) * HW_ + off] : 0.f;
      }
    }

    // ---- P1: W/H pools for 70 local channels from sx[cur] ----
    for (int i = t; i < 70 * 7; i += 256) {
      int lc = i / 7, k = i % 7;
      int base = CHB(lc);
      float s1 = 0.f, m1 = -3.4e38f, s2 = 0.f, m2 = -3.4e38f;
      #pragma unroll
      for (int jj = 0; jj < 7; ++jj) {
        float a = sxc[base + k * 7 + jj]; s1 += a; m1 = fmaxf(m1, a);  // h=k vary w
        float b = sxc[base + jj * 7 + k]; s2 += b; m2 = fmaxf(m2, b);  // w=k vary h
      }
      float* pb = (k < 4) ? pool_lo : pool_hi;
      int kk = k & 3;
      pb[(0 * 70 + lc) * 4 + kk] = s1 * (1.f / 7.f);
      pb[(1 * 70 + lc) * 4 + kk] = m1;
      pb[(2 * 70 + lc) * 4 + kk] = s2 * (1.f / 7.f);
      pb[(3 * 70 + lc) * 4 + kk] = m2;
    }
    __syncthreads();

    // ---- P2: conv (b128 rows + broadcast weights); thread = (conv,i2,cl) ----
    {
      const int f = conv * 2 + i2;
      const float* Wb = s_w + i2 * 56;
      float acc[7] = {0.f, 0.f, 0.f, 0.f, 0.f, 0.f, 0.f};
      #pragma unroll
      for (int p = 0; p < 7; ++p) {
        int ri = (f * 70 + cl + p) * 4;
        float4 r0 = *(const float4*)(pool_lo + ri);
        float4 r1 = *(const float4*)(pool_hi + ri);
        float row[7] = {r0.x, r0.y, r0.z, r0.w, r1.x, r1.y, r1.z};
        float4 w0 = *(const float4*)(Wb + p * 8);
        float4 w1 = *(const float4*)(Wb + p * 8 + 4);
        float wr[7] = {w0.x, w0.y, w0.z, w0.w, w1.x, w1.y, w1.z};
        #pragma unroll
        for (int q = 0; q < 7; ++q)
          #pragma unroll
          for (int k = 0; k < 7; ++k) {
            int c = k + q - 3;               // compile-time after unroll
            if (c >= 0 && c < 7) acc[k] += row[c] * wr[q];
          }
      }
      float fsum[7];
      #pragma unroll
      for (int k = 0; k < 7; ++k) fsum[k] = acc[k] + __shfl_xor(acc[k], 2, 64);
      if (i2 == 0) {
        float* gp = (conv ? gcw : gch) + cl * 7;
        #pragma unroll
        for (int k = 0; k < 7; ++k) {
          float y = (fsum[k] + cb0 - rm_bn) * sc_bn + sh_bn;
          y = fmaxf(y, 0.f);
          gp[k] = 1.f / (1.f + __expf(-y));
        }
      }
    }

    // ---- write prefetched tile j+1 into sx[nxt] ----
    if (j < TPB - 1) {
      float* sxn = sx[nxt];
      float4* sxnv = (float4*)(sxn + 148);
      if (t < 196) { sxnv[t] = q0; sxnv[t + 196] = q1; sxnv[t + 392] = q2; sxnv[t + 588] = q3; }
      if (t < 147) {
        int lcl = t / 49, off = t % 49;
        sxn[CHB(lcl) + off] = h0;
        sxn[CHB(67 + lcl) + off] = h1;
      }
    }
    __syncthreads();

    // ---- P3: fused multiply from sx[cur], float4 stores ----
    {
      const float4* sxv = (const float4*)(sxc + 148);
      float4* outv = (float4*)(out + ((size_t)n * C_ + c0) * HW_);
      for (int v = t; v < 784; v += 256) {
        float4 q = sxv[v];
        int e0 = v * 4;
        int cj = e0 / 49;
        int hw0 = e0 - cj * 49;
        float r[4] = {q.x, q.y, q.z, q.w};
        #pragma unroll
        for (int jj = 0; jj < 4; ++jj) {
          int hw = hw0 + jj;
          int cjj = cj + (hw >= 49);
          hw -= (hw >= 49) ? 49 : 0;
          int h = (hw * 37) >> 8, w2 = hw - h * 7;
          r[jj] *= (s_ghw[hw] + gch[cjj * 7 + h] + gcw[cjj * 7 + w2]) * (1.f / 3.f);
        }
        outv[v] = make_float4(r[0], r[1], r[2], r[3]);
      }
    }
    // no 3rd barrier (r15-proven): next P1 writes pools / reads sx[nxt],
    // disjoint from P3's reads; next conv's gch writes fenced by next bar1.
  }
}

extern "C" void kernel_launch(void* const* d_in, const int* in_sizes, int n_in,
                              void* d_out, int out_size, void* d_ws, size_t ws_size,
                              hipStream_t stream) {
  const float* x    = (const float*)d_in[0];
  const float* cw   = (const float*)d_in[1];
  const float* cb   = (const float*)d_in[2];
  const float* bnw  = (const float*)d_in[3];
  const float* bnb  = (const float*)d_in[4];
  const float* bnrm = (const float*)d_in[5];
  const float* bnrv = (const float*)d_in[6];
  float* out = (float*)d_out;

  float* psum = (float*)d_ws;                         // N*8*49
  float* pmax = psum + (size_t)N_ * NCHUNK * HW_;     // N*8*49
  float* ghw  = pmax + (size_t)N_ * NCHUNK * HW_;     // N*49

  k_poolc<<<dim3(NCHUNK, N_), 256, 0, stream>>>(x, psum, pmax);
  k_ghw<<<dim3(N_), 64, 0, stream>>>(psum, pmax, cw, cb, bnw, bnb, bnrm, bnrv, ghw);
  k_main_p<<<dim3(NBX, N_), 256, 0, stream>>>(x, ghw, cw, cb, bnw, bnb, bnrm,
                                              bnrv, out);
}

// Round 19
// 76.976 us; speedup vs baseline: 6.1805x; 1.0196x over previous
//
#include <hip/hip_runtime.h>

#define N_ 256
#define C_ 2048
#define HW_ 49
#define CPB 64
#define NCHUNK 8        // 256-ch chunks in k_poolc; also tile-groups in k_main_p

// local-channel base in sx: 70 channels (3 halo low, 64 main, 3 halo high).
// Main chunk starts at 148 (16B-aligned for float4); halo-low at 0, gap at 147.
#define CHB(lc) ((lc) * HW_ + ((lc) >= 3 ? 1 : 0))

// ---------------- kernel 1: channel-pool partials, 256 ch per block (r8) ----------------
__global__ __launch_bounds__(256) void k_poolc(const float* __restrict__ x,
                                               float* __restrict__ psum,
                                               float* __restrict__ pmax) {
  const int bc = blockIdx.x, n = blockIdx.y;
  const int t = threadIdx.x;
  __shared__ __align__(16) float sx[CPB * HW_];
  __shared__ float part_s[HW_][5];
  __shared__ float part_m[HW_][5];

  float sm = 0.f, mx = -3.4e38f;
  const int hw = t / 5, s = t % 5;

  const float4* xv = (const float4*)(x + ((size_t)n * C_ + (size_t)bc * 256) * HW_);
  #pragma unroll
  for (int pass = 0; pass < 4; ++pass) {
    float4* sv = (float4*)sx;
    for (int v = t; v < 784; v += 256) sv[v] = xv[pass * 784 + v];
    __syncthreads();
    if (t < 245) {
      #pragma unroll
      for (int j = 0; j < 13; ++j) {
        int c = s * 13 + j;
        if (c < CPB) { float a = sx[c * HW_ + hw]; sm += a; mx = fmaxf(mx, a); }
      }
    }
    __syncthreads();
  }
  if (t < 245) { part_s[hw][s] = sm; part_m[hw][s] = mx; }
  __syncthreads();
  if (t < HW_) {
    float s2 = 0.f, m2 = -3.4e38f;
    #pragma unroll
    for (int k = 0; k < 5; ++k) { s2 += part_s[t][k]; m2 = fmaxf(m2, part_m[t][k]); }
    size_t o = ((size_t)n * NCHUNK + bc) * HW_ + t;
    psum[o] = s2; pmax[o] = m2;
  }
}

// ---------------- kernel 2: reduce chunks, compute g_hw gate per n ----------------
__global__ __launch_bounds__(64) void k_ghw(const float* __restrict__ psum,
                                            const float* __restrict__ pmax,
                                            const float* __restrict__ cw,
                                            const float* __restrict__ cb,
                                            const float* __restrict__ bnw,
                                            const float* __restrict__ bnb,
                                            const float* __restrict__ bnrm,
                                            const float* __restrict__ bnrv,
                                            float* __restrict__ ghw) {
  const int n = blockIdx.x;
  const int t = threadIdx.x;
  __shared__ float p2c[2][13][13];
  __shared__ float s_cw[98];

  for (int i = t; i < 2 * 13 * 13; i += 64) ((float*)p2c)[i] = 0.f;
  for (int i = t; i < 98; i += 64) s_cw[i] = cw[i];
  __syncthreads();

  if (t < HW_) {
    float sm = 0.f, mx = -3.4e38f;
    const float* ps = psum + (size_t)n * NCHUNK * HW_ + t;
    const float* pm = pmax + (size_t)n * NCHUNK * HW_ + t;
    #pragma unroll
    for (int cc = 0; cc < NCHUNK; ++cc) {
      sm += ps[cc * HW_];
      mx = fmaxf(mx, pm[cc * HW_]);
    }
    p2c[0][t / 7 + 3][t % 7 + 3] = sm * (1.f / C_);
    p2c[1][t / 7 + 3][t % 7 + 3] = mx;
  }
  __syncthreads();

  if (t < HW_) {
    int a = t / 7, b = t % 7;
    float y = cb[0];
    #pragma unroll
    for (int i2 = 0; i2 < 2; ++i2)
      #pragma unroll
      for (int p = 0; p < 7; ++p)
        #pragma unroll
        for (int q = 0; q < 7; ++q)
          y += p2c[i2][a + p][b + q] * s_cw[i2 * 49 + p * 7 + q];
    float sc = bnw[0] * rsqrtf(bnrv[0] + 1e-5f);
    y = (y - bnrm[0]) * sc + bnb[0];
    y = fmaxf(y, 0.f);
    ghw[n * HW_ + t] = 1.f / (1.f + __expf(-y));
  }
}

// ---------------- kernel 3: 4-tile pipelined gates + multiply (r15 optimum) ----------------
// grid (8, N): block owns n and tiles cc = bx*4 .. bx*4+3.
// Per tile: issue next-tile loads (4 float4 + 2 halo floats, uniform guards)
//   -> P1 pools -> bar -> conv (load shadow) -> regs->sx[next] -> bar -> multiply.
// LDS: 2*3432 + 1120 + 1120 + 448 + 448 + 112 + 49 = 10161 fl = 40.6 KB -> 4 blk/CU.
__global__ __launch_bounds__(256, 4) void k_main_p(const float* __restrict__ x,
    const float* __restrict__ ghw,
    const float* __restrict__ cw, const float* __restrict__ cb,
    const float* __restrict__ bnw, const float* __restrict__ bnb,
    const float* __restrict__ bnrm, const float* __restrict__ bnrv,
    float* __restrict__ out) {
  const int bx = blockIdx.x;                  // 0..7
  const int n  = (N_ - 1) - blockIdx.y;       // reverse n: L3-freshest first
  const int t  = threadIdx.x;

  __shared__ __align__(16) float sx[2][3432];
  __shared__ __align__(16) float pool_lo[1120];  // [4][70][4] k=0..3
  __shared__ __align__(16) float pool_hi[1120];  // [4][70][4] k=4..6 (+pad)
  __shared__ float gch[448];
  __shared__ float gcw[448];
  __shared__ __align__(16) float s_w[112];       // [2][7][8] q-padded
  __shared__ float s_ghw[49];

  const int conv = t & 1, i2 = (t >> 1) & 1, cl = t >> 2;
  const int bi = 1 + conv;
  const float cb0 = cb[0];
  const float sc_bn = bnw[bi] * rsqrtf(bnrv[bi] + 1e-5f);
  const float rm_bn = bnrm[bi];
  const float sh_bn = bnb[bi];

  // ---- prologue: params + stage tile 0 into sx[0] ----
  if (t < 112) {
    int i2w = t / 56, rem = t % 56, p = rem / 8, q = rem % 8;
    s_w[t] = (q < 7) ? cw[i2w * 49 + p * 7 + q] : 0.f;
  }
  if (t < HW_) s_ghw[t] = ghw[n * HW_ + t];
  {
    const int c0 = (bx * 4) * CPB;
    for (int i = t; i < 294; i += 256) {        // halo
      int side = i / 147, off = i % 147;
      int lc = side ? (67 + off / HW_) : (off / HW_);
      int c = c0 - 3 + lc;
      float vv = 0.f;
      if (c >= 0 && c < C_) vv = x[((size_t)n * C_ + c) * HW_ + off % HW_];
      sx[0][CHB(lc) + off % HW_] = vv;
    }
    const float4* xv = (const float4*)(x + ((size_t)n * C_ + c0) * HW_);
    float4* sxv = (float4*)(&sx[0][148]);
    for (int v = t; v < 784; v += 256) sxv[v] = xv[v];
  }
  __syncthreads();

  #pragma unroll
  for (int j = 0; j < 4; ++j) {
    const int cur = j & 1, nxt = cur ^ 1;
    const int cc = bx * 4 + j;
    const int c0 = cc * CPB;
    float* sxc = sx[cur];

    // ---- issue next-tile loads (regs live until write below) ----
    float4 q0, q1, q2, q3;
    float h0, h1;
    if (j < 3) {
      const int c0n = (cc + 1) * CPB;
      const float4* xvn = (const float4*)(x + ((size_t)n * C_ + c0n) * HW_);
      if (t < 196) { q0 = xvn[t]; q1 = xvn[t + 196]; q2 = xvn[t + 392]; q3 = xvn[t + 588]; }
      if (t < 147) {
        int lcl = t / 49, off = t % 49;
        int cl_ = c0n - 3 + lcl;
        int ch_ = c0n + CPB + lcl;
        h0 = (cl_ >= 0 && cl_ < C_) ? x[((size_t)n * C_ + cl_) * HW_ + off] : 0.f;
        h1 = (ch_ < C_) ? x[((size_t)n * C_ + ch_) * HW_ + off] : 0.f;
      }
    }

    // ---- P1: W/H pools for 70 local channels from sx[cur] ----
    for (int i = t; i < 70 * 7; i += 256) {
      int lc = i / 7, k = i % 7;
      int base = CHB(lc);
      float s1 = 0.f, m1 = -3.4e38f, s2 = 0.f, m2 = -3.4e38f;
      #pragma unroll
      for (int jj = 0; jj < 7; ++jj) {
        float a = sxc[base + k * 7 + jj]; s1 += a; m1 = fmaxf(m1, a);  // h=k vary w
        float b = sxc[base + jj * 7 + k]; s2 += b; m2 = fmaxf(m2, b);  // w=k vary h
      }
      float* pb = (k < 4) ? pool_lo : pool_hi;
      int kk = k & 3;
      pb[(0 * 70 + lc) * 4 + kk] = s1 * (1.f / 7.f);
      pb[(1 * 70 + lc) * 4 + kk] = m1;
      pb[(2 * 70 + lc) * 4 + kk] = s2 * (1.f / 7.f);
      pb[(3 * 70 + lc) * 4 + kk] = m2;
    }
    __syncthreads();

    // ---- P2: conv (b128 rows + broadcast weights); thread = (conv,i2,cl) ----
    {
      const int f = conv * 2 + i2;
      const float* Wb = s_w + i2 * 56;
      float acc[7] = {0.f, 0.f, 0.f, 0.f, 0.f, 0.f, 0.f};
      #pragma unroll
      for (int p = 0; p < 7; ++p) {
        int ri = (f * 70 + cl + p) * 4;
        float4 r0 = *(const float4*)(pool_lo + ri);
        float4 r1 = *(const float4*)(pool_hi + ri);
        float row[7] = {r0.x, r0.y, r0.z, r0.w, r1.x, r1.y, r1.z};
        float4 w0 = *(const float4*)(Wb + p * 8);
        float4 w1 = *(const float4*)(Wb + p * 8 + 4);
        float wr[7] = {w0.x, w0.y, w0.z, w0.w, w1.x, w1.y, w1.z};
        #pragma unroll
        for (int q = 0; q < 7; ++q)
          #pragma unroll
          for (int k = 0; k < 7; ++k) {
            int c = k + q - 3;               // compile-time after unroll
            if (c >= 0 && c < 7) acc[k] += row[c] * wr[q];
          }
      }
      float fsum[7];
      #pragma unroll
      for (int k = 0; k < 7; ++k) fsum[k] = acc[k] + __shfl_xor(acc[k], 2, 64);
      if (i2 == 0) {
        float* gp = (conv ? gcw : gch) + cl * 7;
        #pragma unroll
        for (int k = 0; k < 7; ++k) {
          float y = (fsum[k] + cb0 - rm_bn) * sc_bn + sh_bn;
          y = fmaxf(y, 0.f);
          gp[k] = 1.f / (1.f + __expf(-y));
        }
      }
    }

    // ---- write prefetched tile j+1 into sx[nxt] ----
    if (j < 3) {
      float* sxn = sx[nxt];
      float4* sxnv = (float4*)(sxn + 148);
      if (t < 196) { sxnv[t] = q0; sxnv[t + 196] = q1; sxnv[t + 392] = q2; sxnv[t + 588] = q3; }
      if (t < 147) {
        int lcl = t / 49, off = t % 49;
        sxn[CHB(lcl) + off] = h0;
        sxn[CHB(67 + lcl) + off] = h1;
      }
    }
    __syncthreads();

    // ---- P3: fused multiply from sx[cur], float4 stores ----
    {
      const float4* sxv = (const float4*)(sxc + 148);
      float4* outv = (float4*)(out + ((size_t)n * C_ + c0) * HW_);
      for (int v = t; v < 784; v += 256) {
        float4 q = sxv[v];
        int e0 = v * 4;
        int cj = e0 / 49;
        int hw0 = e0 - cj * 49;
        float r[4] = {q.x, q.y, q.z, q.w};
        #pragma unroll
        for (int jj = 0; jj < 4; ++jj) {
          int hw = hw0 + jj;
          int cjj = cj + (hw >= 49);
          hw -= (hw >= 49) ? 49 : 0;
          int h = (hw * 37) >> 8, w2 = hw - h * 7;
          r[jj] *= (s_ghw[hw] + gch[cjj * 7 + h] + gcw[cjj * 7 + w2]) * (1.f / 3.f);
        }
        outv[v] = make_float4(r[0], r[1], r[2], r[3]);
      }
    }
    // no 3rd barrier (r15-proven): next P1 writes pools / reads sx[nxt],
    // disjoint from P3's reads; next conv's gch writes fenced by next bar1.
  }
}

extern "C" void kernel_launch(void* const* d_in, const int* in_sizes, int n_in,
                              void* d_out, int out_size, void* d_ws, size_t ws_size,
                              hipStream_t stream) {
  const float* x    = (const float*)d_in[0];
  const float* cw   = (const float*)d_in[1];
  const float* cb   = (const float*)d_in[2];
  const float* bnw  = (const float*)d_in[3];
  const float* bnb  = (const float*)d_in[4];
  const float* bnrm = (const float*)d_in[5];
  const float* bnrv = (const float*)d_in[6];
  float* out = (float*)d_out;

  float* psum = (float*)d_ws;                         // N*8*49
  float* pmax = psum + (size_t)N_ * NCHUNK * HW_;     // N*8*49
  float* ghw  = pmax + (size_t)N_ * NCHUNK * HW_;     // N*49

  k_poolc<<<dim3(NCHUNK, N_), 256, 0, stream>>>(x, psum, pmax);
  k_ghw<<<dim3(N_), 64, 0, stream>>>(psum, pmax, cw, cb, bnw, bnb, bnrm, bnrv, ghw);
  k_main_p<<<dim3(NCHUNK, N_), 256, 0, stream>>>(x, ghw, cw, cb, bnw, bnb, bnrm,
                                                 bnrv, out);
}